// Round 13
// baseline (445.777 us; speedup 1.0000x reference)
//
#include <hip/hip_runtime.h>
#include <hip/hip_bf16.h>

// Problem constants
#define BATCH 4096
#define IN_SZ 512
#define HID_SZ 2048
#define OUT_SZ 512
#define NLAYER 4
#define INNER 2560        // 512 + 2048
#define NKT (INNER / 64)  // 40 K-tiles of 64

// R9 GEMM (best: 300.5 us total) + 5th wave doing NEXT-layer weight
// conversion, barrier-matched (121 s_barriers in both paths).
// Tile: BM=128 x BN=160, BK=64; grid 32x16 = 512 blocks = 2/CU.
// Waves 0-3 (2M x 2N, 64x80 each): 3-barrier K-loop (see R9 derivation).
// Wave 4: converts 50 float4/lane of fp32 weights -> bf16, 2/barrier-slot,
// 1-slot software pipeline (load slot s, store slot s+1).

typedef __attribute__((ext_vector_type(8))) short bf16x8;
typedef __attribute__((ext_vector_type(4))) float f32x4;

__device__ __forceinline__ unsigned short f2bf(float f) {
  unsigned int u = __float_as_uint(f);
  u += 0x7fff + ((u >> 16) & 1);  // RNE
  return (unsigned short)(u >> 16);
}

__device__ __forceinline__ void gload16(const void* g, void* l) {
  __builtin_amdgcn_global_load_lds(
      (const __attribute__((address_space(1))) unsigned int*)g,
      (__attribute__((address_space(3))) unsigned int*)l,
      16, 0, 0);
}

// ---------------- prep kernel: W0 conversion + combined build ----------------
#define NW14 1638400   // one 2560x2560 layer / 4
#define NC4  2621440   // combined 4096x2560 / 4
__global__ void prep(const float* __restrict__ W0, const float* __restrict__ x,
                     const float* __restrict__ h, unsigned short* __restrict__ Wdst,
                     unsigned short* __restrict__ cdst) {
  const int total = NW14 + NC4;
  int i = blockIdx.x * blockDim.x + threadIdx.x;
  const int stride = gridDim.x * blockDim.x;
  for (; i < total; i += stride) {
    const float* src;
    unsigned short* dst;
    if (i < NW14) {
      src = W0 + (long)i * 4;
      dst = Wdst + (long)i * 4;
    } else {
      const int j = i - NW14;
      const int row = j / (INNER / 4);
      const int c4 = j - row * (INNER / 4);
      src = (c4 < IN_SZ / 4) ? (x + (long)row * IN_SZ + c4 * 4)
                             : (h + (long)row * HID_SZ + (c4 - IN_SZ / 4) * 4);
      dst = cdst + (long)j * 4;
    }
    float4 v = *reinterpret_cast<const float4*>(src);
    ushort4 o;
    o.x = f2bf(v.x); o.y = f2bf(v.y); o.z = f2bf(v.z); o.w = f2bf(v.w);
    *reinterpret_cast<ushort4*>(dst) = o;
  }
}

// ---------------- 128x160 3-barrier GEMM + cvt wave --------------------------
// See R9 for the hazard derivation. Barrier count (gemm path): prologue 1 +
// 40 x 3 = 121. The cvt wave executes exactly 121 s_barriers.

#define STAGE_U(kt, u, buf) do {                                              \
  if ((u) < 4) {                                                              \
    const int base_ = (u) * 32 + w * 8;                                       \
    gload16(A + (long)(row0 + base_ + srow) * INNER + (kt) * 64 + srcsw,      \
            (void*)(&lds[buf][base_ * 64]));                                  \
  } else {                                                                    \
    const int base_ = ((u) - 4) * 32 + w * 8;                                 \
    gload16(B + (long)(col0 + base_ + srow) * INNER + (kt) * 64 + srcsw,      \
            (void*)(&lds[buf][8192 + base_ * 64]));                           \
  } } while (0)

#define LOAD_AF(dst, mh, buf) do {                                           \
  const unsigned short* Ar_ = &lds[buf][0];                                  \
  _Pragma("unroll")                                                          \
  for (int m_ = 0; m_ < 2; ++m_) {                                           \
    int r_ = wr * 64 + (mh) * 32 + m_ * 16 + fr;                             \
    dst[m_][0] = *(const bf16x8*)(Ar_ + r_ * 64 + csw0);                     \
    dst[m_][1] = *(const bf16x8*)(Ar_ + r_ * 64 + csw1);                     \
  } } while (0)

#define LOAD_BQA(dst, buf) do {                                              \
  const unsigned short* Br_ = &lds[buf][8192];                               \
  _Pragma("unroll")                                                          \
  for (int n_ = 0; n_ < 3; ++n_) {                                           \
    int r_ = wcn * 80 + n_ * 16 + fr;                                        \
    dst[n_][0] = *(const bf16x8*)(Br_ + r_ * 64 + csw0);                     \
    dst[n_][1] = *(const bf16x8*)(Br_ + r_ * 64 + csw1);                     \
  } } while (0)

#define LOAD_BQB(dst, buf) do {                                              \
  const unsigned short* Br_ = &lds[buf][8192];                               \
  _Pragma("unroll")                                                          \
  for (int n_ = 0; n_ < 2; ++n_) {                                           \
    int r_ = wcn * 80 + (3 + n_) * 16 + fr;                                  \
    dst[n_][0] = *(const bf16x8*)(Br_ + r_ * 64 + csw0);                     \
    dst[n_][1] = *(const bf16x8*)(Br_ + r_ * 64 + csw1);                     \
  } } while (0)

#define MF_A(af, bq, mh) do {                                                 \
  __builtin_amdgcn_s_setprio(1);                                              \
  _Pragma("unroll")                                                           \
  for (int m_ = 0; m_ < 2; ++m_)                                              \
    _Pragma("unroll")                                                         \
    for (int n_ = 0; n_ < 3; ++n_) {                                          \
      acc[(mh) * 2 + m_][n_] = __builtin_amdgcn_mfma_f32_16x16x32_bf16(       \
          af[m_][0], bq[n_][0], acc[(mh) * 2 + m_][n_], 0, 0, 0);             \
      acc[(mh) * 2 + m_][n_] = __builtin_amdgcn_mfma_f32_16x16x32_bf16(       \
          af[m_][1], bq[n_][1], acc[(mh) * 2 + m_][n_], 0, 0, 0);             \
    }                                                                         \
  __builtin_amdgcn_s_setprio(0);                                              \
} while (0)

#define MF_B(af, bq, mh) do {                                                 \
  __builtin_amdgcn_s_setprio(1);                                              \
  _Pragma("unroll")                                                           \
  for (int m_ = 0; m_ < 2; ++m_)                                              \
    _Pragma("unroll")                                                         \
    for (int n_ = 0; n_ < 2; ++n_) {                                          \
      acc[(mh) * 2 + m_][3 + n_] = __builtin_amdgcn_mfma_f32_16x16x32_bf16(   \
          af[m_][0], bq[n_][0], acc[(mh) * 2 + m_][3 + n_], 0, 0, 0);         \
      acc[(mh) * 2 + m_][3 + n_] = __builtin_amdgcn_mfma_f32_16x16x32_bf16(   \
          af[m_][1], bq[n_][1], acc[(mh) * 2 + m_][3 + n_], 0, 0, 0);         \
    }                                                                         \
  __builtin_amdgcn_s_setprio(0);                                              \
} while (0)

#define SB() __builtin_amdgcn_sched_barrier(0)

#define TILE_BODY(d, AC, QC, AN, QN) do {                                     \
  const int T = T2 + (d);                                                     \
  const int kt1 = (T + 1 < NKT) ? T + 1 : NKT - 1;  /* clamp: dup, benign */  \
  const int kt2 = (T + 2 < NKT) ? T + 2 : NKT - 1;                            \
  /* P0: issue bqB(T); stage T+1 {u6,u7,u8} -> d^1; MFMA Q0 = AC x QC */      \
  LOAD_BQB(bqB, d);                                                           \
  STAGE_U(kt1, 6, (d) ^ 1); STAGE_U(kt1, 7, (d) ^ 1); STAGE_U(kt1, 8, (d) ^ 1); \
  SB();                                                                       \
  asm volatile("s_waitcnt lgkmcnt(4)" ::: "memory");  /* AC,QC done */        \
  SB();                                                                       \
  MF_A(AC, QC, 0);                                                            \
  /* P1: issue afB(T); stage T+1 {u0,u1} -> d^1; MFMA Q1 = AC x bqB */        \
  LOAD_AF(afB, 1, d);                                                         \
  STAGE_U(kt1, 0, (d) ^ 1); STAGE_U(kt1, 1, (d) ^ 1);                         \
  SB();                                                                       \
  asm volatile("s_waitcnt lgkmcnt(4)" ::: "memory");  /* bqB done */          \
  SB();                                                                       \
  MF_B(AC, bqB, 0);                                                           \
  __builtin_amdgcn_s_barrier();  /* P1e: B reads of buf d retired */          \
  /* P2: stage T+2 {u4,u5} -> d (B rows 0-63); MFMA Q2 = afB x bqB */         \
  STAGE_U(kt2, 4, d); STAGE_U(kt2, 5, d);                                     \
  SB();                                                                       \
  asm volatile("s_waitcnt lgkmcnt(0)" ::: "memory");  /* afB done */          \
  SB();                                                                       \
  MF_B(afB, bqB, 1);                                                          \
  __builtin_amdgcn_s_barrier();  /* P2e: A-mh1 reads retired */               \
  /* P3: stage T+2 {u2,u3} -> d (A rows 64-127); validate T+1; MFMA Q3 */     \
  STAGE_U(kt2, 2, d); STAGE_U(kt2, 3, d);                                     \
  asm volatile("s_waitcnt vmcnt(4)" ::: "memory");  /* T+1 fully landed */    \
  __builtin_amdgcn_s_barrier();  /* P3b: T+1 visible to all waves */          \
  SB();                                                                       \
  LOAD_AF(AN, 0, (d) ^ 1);                                                    \
  LOAD_BQA(QN, (d) ^ 1);                                                      \
  SB();  /* pin read-issue before the MFMA cluster */                         \
  MF_A(afB, QC, 1);                                                           \
} while (0)

// MODE 0: relu -> bf16 C; MODE 1: fused heads (f32 out + tanh f32 hidden).
// cvtA/cvtB/csplit/cnk: wave-4 conversion job (cnk = float4 units per lane).
template <int MODE>
__global__ __launch_bounds__(320, 2)
void gemm8(const unsigned short* __restrict__ A, const unsigned short* __restrict__ B,
           const float* __restrict__ bias0, const float* __restrict__ bias1,
           void* __restrict__ C,
           const float* __restrict__ cvtA, const float* __restrict__ cvtB,
           int csplit, int cnk, unsigned short* __restrict__ cvtD) {
  __shared__ unsigned short lds[2][18432];  // 72 KiB: A [0,8192), B [8192,18432)

  const int tid = threadIdx.x;
  const int w = tid >> 6;   // waves 0-3 gemm, wave 4 cvt
  const int lane = tid & 63;
  const int flat = blockIdx.x;

  if (w == 4) {
    // ---- conversion wave: exactly 121 s_barriers, 2 float4 units/slot ----
    const long base = (long)flat * 64 + lane;
    const long stride = 32768;  // 512 blocks x 64 lanes
    int k = 0;
    float4 p0, p1;
    long u0 = 0, u1 = 0;
    bool have = false;
    for (int s = 0; s < 121; ++s) {
      if (have) {
        ushort4 o0, o1;
        o0.x = f2bf(p0.x); o0.y = f2bf(p0.y); o0.z = f2bf(p0.z); o0.w = f2bf(p0.w);
        o1.x = f2bf(p1.x); o1.y = f2bf(p1.y); o1.z = f2bf(p1.z); o1.w = f2bf(p1.w);
        *reinterpret_cast<ushort4*>(cvtD + u0 * 4) = o0;
        *reinterpret_cast<ushort4*>(cvtD + u1 * 4) = o1;
        have = false;
      }
      if (k < cnk) {
        u0 = base + (long)k * stride;
        u1 = base + (long)(k + 1) * stride;
        {
          const long e = u0 * 4;
          const int row = (int)(e / INNER);
          const int col = (int)(e - (long)row * INNER);
          const float* sp = (row < csplit) ? (cvtA + (long)row * INNER + col)
                                           : (cvtB + (long)(row - csplit) * INNER + col);
          p0 = *reinterpret_cast<const float4*>(sp);
        }
        {
          const long e = u1 * 4;
          const int row = (int)(e / INNER);
          const int col = (int)(e - (long)row * INNER);
          const float* sp = (row < csplit) ? (cvtA + (long)row * INNER + col)
                                           : (cvtB + (long)(row - csplit) * INNER + col);
          p1 = *reinterpret_cast<const float4*>(sp);
        }
        k += 2;
        have = true;
      }
      __builtin_amdgcn_s_barrier();
    }
    if (have) {
      ushort4 o0, o1;
      o0.x = f2bf(p0.x); o0.y = f2bf(p0.y); o0.z = f2bf(p0.z); o0.w = f2bf(p0.w);
      o1.x = f2bf(p1.x); o1.y = f2bf(p1.y); o1.z = f2bf(p1.z); o1.w = f2bf(p1.w);
      *reinterpret_cast<ushort4*>(cvtD + u0 * 4) = o0;
      *reinterpret_cast<ushort4*>(cvtD + u1 * 4) = o1;
    }
    return;
  }

  // ---- gemm waves (0-3): exact R9 structure ----
  const int xcd = flat & 7;
  const int local = flat >> 3;           // 0..63
  const int nb = xcd * 2 + (local & 1);  // 16 N-blocks
  const int mb = local >> 1;             // 32 M-blocks
  const int row0 = mb * 128, col0 = nb * 160;
  const int wr = w >> 1, wcn = w & 1;

  const int srow = lane >> 3;
  const int srcsw = ((((lane & 7) << 4) ^ ((lane >> 3) << 4)) >> 1);

  const int fr = lane & 15;
  const int csw0 = ((((lane >> 4) << 4)) ^ ((lane & 7) << 4)) >> 1;       // kk=0
  const int csw1 = ((64 + ((lane >> 4) << 4)) ^ ((lane & 7) << 4)) >> 1;  // kk=1

  f32x4 acc[4][5] = {};
  bf16x8 afA0[2][2], afA1[2][2], afB[2][2];
  bf16x8 bqA0[3][2], bqA1[3][2], bqB[2][2];

  // prologue: tile 0 fully (9 units) + tile 1's {u4,u5,u2,u3}; frag reads
  STAGE_U(0, 0, 0); STAGE_U(0, 1, 0); STAGE_U(0, 2, 0); STAGE_U(0, 3, 0);
  STAGE_U(0, 4, 0); STAGE_U(0, 5, 0); STAGE_U(0, 6, 0); STAGE_U(0, 7, 0);
  STAGE_U(0, 8, 0);
  STAGE_U(1, 4, 1); STAGE_U(1, 5, 1); STAGE_U(1, 2, 1); STAGE_U(1, 3, 1);
  asm volatile("s_waitcnt vmcnt(4)" ::: "memory");  // tile 0 landed
  __builtin_amdgcn_s_barrier();                      // barrier #1
  SB();
  LOAD_AF(afA0, 0, 0);
  LOAD_BQA(bqA0, 0);
  SB();

  for (int T2 = 0; T2 < NKT; T2 += 2) {   // 20 iters x 2 bodies x 3 barriers
    TILE_BODY(0, afA0, bqA0, afA1, bqA1);
    TILE_BODY(1, afA1, bqA1, afA0, bqA0);
  }
  asm volatile("s_waitcnt vmcnt(0)" ::: "memory");

  // epilogue: C/D layout col = lane&15, row = (lane>>4)*4 + j
  const int erow = row0 + wr * 64 + ((lane >> 4) << 2);
  const int ecol = col0 + wcn * 80 + fr;
  if (MODE == 0) {
    unsigned short* Co = (unsigned short*)C;
#pragma unroll
    for (int n = 0; n < 5; ++n) {
      const int col = ecol + n * 16;
      const float bv = bias0[col];
#pragma unroll
      for (int m = 0; m < 4; ++m) {
        const int row = erow + m * 16;
#pragma unroll
        for (int j = 0; j < 4; ++j) {
          float v = acc[m][n][j] + bv;
          v = fmaxf(v, 0.0f);
          Co[(long)(row + j) * INNER + col] = f2bf(v);
        }
      }
    }
  } else {
    float* outO = (float*)C;                          // [4096,512]
    float* outH = (float*)C + (long)BATCH * OUT_SZ;   // [4096,2048]
#pragma unroll
    for (int n = 0; n < 5; ++n) {
      const int col = ecol + n * 16;
      if (col < OUT_SZ) {
        const float bv = bias0[col];
#pragma unroll
        for (int m = 0; m < 4; ++m) {
          const int row = erow + m * 16;
#pragma unroll
          for (int j = 0; j < 4; ++j)
            outO[(long)(row + j) * OUT_SZ + col] = acc[m][n][j] + bv;
        }
      } else {
        const int hc = col - OUT_SZ;
        const float bv = bias1[hc];
#pragma unroll
        for (int m = 0; m < 4; ++m) {
          const int row = erow + m * 16;
#pragma unroll
          for (int j = 0; j < 4; ++j)
            outH[(long)(row + j) * HID_SZ + hc] = tanhf(acc[m][n][j] + bv);
        }
      }
    }
  }
}

// ---------------- launcher ----------------

extern "C" void kernel_launch(void* const* d_in, const int* in_sizes, int n_in,
                              void* d_out, int out_size, void* d_ws, size_t ws_size,
                              hipStream_t stream) {
  const float* x   = (const float*)d_in[0];
  const float* h   = (const float*)d_in[1];
  const float* Wl  = (const float*)d_in[2];  // [4,2560,2560]
  const float* bl  = (const float*)d_in[3];  // [4,2560]
  const float* Wih = (const float*)d_in[4];  // [2048,2560]
  const float* bih = (const float*)d_in[5];  // [2048]
  const float* Wio = (const float*)d_in[6];  // [512,2560]
  const float* bio = (const float*)d_in[7];  // [512]

  unsigned short* ws   = (unsigned short*)d_ws;
  unsigned short* Wlb  = ws;                                   // 4*2560*2560 bf16
  unsigned short* Whb  = Wlb + (long)NLAYER * INNER * INNER;   // fused heads [2560][2560]
  unsigned short* act0 = Whb + (long)INNER * INNER;
  unsigned short* act1 = act0 + (long)BATCH * INNER;

  const long WSZ = (long)INNER * INNER;  // elems per square layer
  const int BIG = 1 << 30;               // "no split" sentinel

  // prologue: convert W0 + build combined (serial, ~12-16 us)
  prep<<<2048, 256, 0, stream>>>(Wl, x, h, Wlb, act0);

  // 4 square layers; layer l's wave-4 converts W[l+1] (l=3 -> fused heads)
  unsigned short* a_in = act0;
  unsigned short* a_out = act1;
  for (int l = 0; l < NLAYER; ++l) {
    const float* cA; const float* cB; int split; unsigned short* cD;
    if (l < NLAYER - 1) {
      cA = Wl + (l + 1) * WSZ; cB = cA; split = BIG; cD = Wlb + (l + 1) * WSZ;
    } else {
      cA = Wio; cB = Wih; split = OUT_SZ; cD = Whb;  // fused heads
    }
    gemm8<0><<<512, 320, 0, stream>>>(a_in, Wlb + (long)l * WSZ,
                                      bl + (long)l * INNER, nullptr, a_out,
                                      cA, cB, split, 50, cD);
    unsigned short* t = a_in; a_in = a_out; a_out = t;
  }

  // fused heads: output (cols 0-511) + tanh hidden (cols 512-2559); no cvt
  gemm8<1><<<512, 320, 0, stream>>>(a_in, Whb, bio, bih, d_out,
                                    Wl, Wl, BIG, 0, Wlb);
}

// Round 14
// 306.892 us; speedup vs baseline: 1.4526x; 1.4526x over previous
//
#include <hip/hip_runtime.h>
#include <hip/hip_bf16.h>

// Problem constants
#define BATCH 4096
#define IN_SZ 512
#define HID_SZ 2048
#define OUT_SZ 512
#define NLAYER 4
#define INNER 2560        // 512 + 2048
#define NKT (INNER / 64)  // 40 K-tiles of 64

// R9 GEMM (best) + COALESCED EPILOGUE via LDS bounce.
// Tile: BM=128 x BN=160, BK=64; grid 32x16 = 512 blocks = 2/CU.
// 256 threads = 4 waves (2M x 2N), per-wave 64x80. 3 barriers/K-tile (R9
// hazard derivation). Epilogue: acc -> LDS (40KB) -> full-line global
// stores (R9's per-thread 2B strided stores caused 2.3x write amplification
// + read-for-ownership fetches: WRITE 48.6MB vs 21MB output).

typedef __attribute__((ext_vector_type(8))) short bf16x8;
typedef __attribute__((ext_vector_type(4))) float f32x4;

__device__ __forceinline__ unsigned short f2bf(float f) {
  unsigned int u = __float_as_uint(f);
  u += 0x7fff + ((u >> 16) & 1);  // RNE
  return (unsigned short)(u >> 16);
}

__device__ __forceinline__ void gload16(const void* g, void* l) {
  __builtin_amdgcn_global_load_lds(
      (const __attribute__((address_space(1))) unsigned int*)g,
      (__attribute__((address_space(3))) unsigned int*)l,
      16, 0, 0);
}

// ---------------- conversion kernels ----------------

#define NWL4  6553600   // Wl  / 4
#define NWO4  327680    // Wio / 4
#define NWH4  1310720   // Wih / 4
__global__ void cvt_all(const float* __restrict__ Wl, const float* __restrict__ Wih,
                        const float* __restrict__ Wio, unsigned short* __restrict__ dst) {
  const int n4 = NWL4 + NWO4 + NWH4;
  int i = blockIdx.x * blockDim.x + threadIdx.x;
  const int stride = gridDim.x * blockDim.x;
  for (; i < n4; i += stride) {
    const float* src;
    long off4;
    if (i < NWL4) { src = Wl; off4 = i; }
    else if (i < NWL4 + NWO4) { src = Wio; off4 = i - NWL4; }
    else { src = Wih; off4 = i - NWL4 - NWO4; }
    float4 v = *reinterpret_cast<const float4*>(src + off4 * 4);
    ushort4 o;
    o.x = f2bf(v.x); o.y = f2bf(v.y); o.z = f2bf(v.z); o.w = f2bf(v.w);
    *reinterpret_cast<ushort4*>(dst + (long)i * 4) = o;
  }
}

__global__ void build_combined(const float* __restrict__ x,
                               const float* __restrict__ h,
                               unsigned short* __restrict__ out) {
  const int n4 = BATCH * INNER / 4;
  int i = blockIdx.x * blockDim.x + threadIdx.x;
  const int stride = gridDim.x * blockDim.x;
  for (; i < n4; i += stride) {
    int row = i / (INNER / 4);
    int c4 = i - row * (INNER / 4);
    const float* src = (c4 < IN_SZ / 4) ? (x + (long)row * IN_SZ + c4 * 4)
                                        : (h + (long)row * HID_SZ + (c4 - IN_SZ / 4) * 4);
    float4 v = *reinterpret_cast<const float4*>(src);
    ushort4 o;
    o.x = f2bf(v.x); o.y = f2bf(v.y); o.z = f2bf(v.z); o.w = f2bf(v.w);
    *reinterpret_cast<ushort4*>(out + (long)i * 4) = o;
  }
}

// ---------------- 128x160 3-barrier GEMM (R9) --------------------------------

#define STAGE_U(kt, u, buf) do {                                              \
  if ((u) < 4) {                                                              \
    const int base_ = (u) * 32 + w * 8;                                       \
    gload16(A + (long)(row0 + base_ + srow) * INNER + (kt) * 64 + srcsw,      \
            (void*)(&lds[buf][base_ * 64]));                                  \
  } else {                                                                    \
    const int base_ = ((u) - 4) * 32 + w * 8;                                 \
    gload16(B + (long)(col0 + base_ + srow) * INNER + (kt) * 64 + srcsw,      \
            (void*)(&lds[buf][8192 + base_ * 64]));                           \
  } } while (0)

#define LOAD_AF(dst, mh, buf) do {                                           \
  const unsigned short* Ar_ = &lds[buf][0];                                  \
  _Pragma("unroll")                                                          \
  for (int m_ = 0; m_ < 2; ++m_) {                                           \
    int r_ = wr * 64 + (mh) * 32 + m_ * 16 + fr;                             \
    dst[m_][0] = *(const bf16x8*)(Ar_ + r_ * 64 + csw0);                     \
    dst[m_][1] = *(const bf16x8*)(Ar_ + r_ * 64 + csw1);                     \
  } } while (0)

#define LOAD_BQA(dst, buf) do {                                              \
  const unsigned short* Br_ = &lds[buf][8192];                               \
  _Pragma("unroll")                                                          \
  for (int n_ = 0; n_ < 3; ++n_) {                                           \
    int r_ = wcn * 80 + n_ * 16 + fr;                                        \
    dst[n_][0] = *(const bf16x8*)(Br_ + r_ * 64 + csw0);                     \
    dst[n_][1] = *(const bf16x8*)(Br_ + r_ * 64 + csw1);                     \
  } } while (0)

#define LOAD_BQB(dst, buf) do {                                              \
  const unsigned short* Br_ = &lds[buf][8192];                               \
  _Pragma("unroll")                                                          \
  for (int n_ = 0; n_ < 2; ++n_) {                                           \
    int r_ = wcn * 80 + (3 + n_) * 16 + fr;                                  \
    dst[n_][0] = *(const bf16x8*)(Br_ + r_ * 64 + csw0);                     \
    dst[n_][1] = *(const bf16x8*)(Br_ + r_ * 64 + csw1);                     \
  } } while (0)

#define MF_A(af, bq, mh) do {                                                 \
  __builtin_amdgcn_s_setprio(1);                                              \
  _Pragma("unroll")                                                           \
  for (int m_ = 0; m_ < 2; ++m_)                                              \
    _Pragma("unroll")                                                         \
    for (int n_ = 0; n_ < 3; ++n_) {                                          \
      acc[(mh) * 2 + m_][n_] = __builtin_amdgcn_mfma_f32_16x16x32_bf16(       \
          af[m_][0], bq[n_][0], acc[(mh) * 2 + m_][n_], 0, 0, 0);             \
      acc[(mh) * 2 + m_][n_] = __builtin_amdgcn_mfma_f32_16x16x32_bf16(       \
          af[m_][1], bq[n_][1], acc[(mh) * 2 + m_][n_], 0, 0, 0);             \
    }                                                                         \
  __builtin_amdgcn_s_setprio(0);                                              \
} while (0)

#define MF_B(af, bq, mh) do {                                                 \
  __builtin_amdgcn_s_setprio(1);                                              \
  _Pragma("unroll")                                                           \
  for (int m_ = 0; m_ < 2; ++m_)                                              \
    _Pragma("unroll")                                                         \
    for (int n_ = 0; n_ < 2; ++n_) {                                          \
      acc[(mh) * 2 + m_][3 + n_] = __builtin_amdgcn_mfma_f32_16x16x32_bf16(   \
          af[m_][0], bq[n_][0], acc[(mh) * 2 + m_][3 + n_], 0, 0, 0);         \
      acc[(mh) * 2 + m_][3 + n_] = __builtin_amdgcn_mfma_f32_16x16x32_bf16(   \
          af[m_][1], bq[n_][1], acc[(mh) * 2 + m_][3 + n_], 0, 0, 0);         \
    }                                                                         \
  __builtin_amdgcn_s_setprio(0);                                              \
} while (0)

#define SB() __builtin_amdgcn_sched_barrier(0)

#define TILE_BODY(d, AC, QC, AN, QN) do {                                     \
  const int T = T2 + (d);                                                     \
  const int kt1 = (T + 1 < NKT) ? T + 1 : NKT - 1;  /* clamp: dup, benign */  \
  const int kt2 = (T + 2 < NKT) ? T + 2 : NKT - 1;                            \
  /* P0: issue bqB(T); stage T+1 {u6,u7,u8} -> d^1; MFMA Q0 = AC x QC */      \
  LOAD_BQB(bqB, d);                                                           \
  STAGE_U(kt1, 6, (d) ^ 1); STAGE_U(kt1, 7, (d) ^ 1); STAGE_U(kt1, 8, (d) ^ 1); \
  SB();                                                                       \
  asm volatile("s_waitcnt lgkmcnt(4)" ::: "memory");  /* AC,QC done */        \
  SB();                                                                       \
  MF_A(AC, QC, 0);                                                            \
  /* P1: issue afB(T); stage T+1 {u0,u1} -> d^1; MFMA Q1 = AC x bqB */        \
  LOAD_AF(afB, 1, d);                                                         \
  STAGE_U(kt1, 0, (d) ^ 1); STAGE_U(kt1, 1, (d) ^ 1);                         \
  SB();                                                                       \
  asm volatile("s_waitcnt lgkmcnt(4)" ::: "memory");  /* bqB done */          \
  SB();                                                                       \
  MF_B(AC, bqB, 0);                                                           \
  __builtin_amdgcn_s_barrier();  /* P1e: B reads of buf d retired */          \
  /* P2: stage T+2 {u4,u5} -> d (B rows 0-63); MFMA Q2 = afB x bqB */         \
  STAGE_U(kt2, 4, d); STAGE_U(kt2, 5, d);                                     \
  SB();                                                                       \
  asm volatile("s_waitcnt lgkmcnt(0)" ::: "memory");  /* afB done */          \
  SB();                                                                       \
  MF_B(afB, bqB, 1);                                                          \
  __builtin_amdgcn_s_barrier();  /* P2e: A-mh1 reads retired */               \
  /* P3: stage T+2 {u2,u3} -> d (A rows 64-127); validate T+1; MFMA Q3 */     \
  STAGE_U(kt2, 2, d); STAGE_U(kt2, 3, d);                                     \
  asm volatile("s_waitcnt vmcnt(4)" ::: "memory");  /* T+1 fully landed */    \
  __builtin_amdgcn_s_barrier();  /* P3b: T+1 visible to all waves */          \
  SB();                                                                       \
  LOAD_AF(AN, 0, (d) ^ 1);                                                    \
  LOAD_BQA(QN, (d) ^ 1);                                                      \
  SB();  /* pin read-issue before the MFMA cluster */                         \
  MF_A(afB, QC, 1);                                                           \
} while (0)

template <int MODE>
__global__ __launch_bounds__(256, 2)
void gemm8(const unsigned short* __restrict__ A, const unsigned short* __restrict__ B,
           const float* __restrict__ bias0, const float* __restrict__ bias1,
           void* __restrict__ C) {
  __shared__ unsigned short lds[2][18432];  // 72 KiB: A [0,8192), B [8192,18432)

  const int tid = threadIdx.x;
  const int w = tid >> 6;   // 4 waves
  const int lane = tid & 63;

  // XCD mapping: 512 blocks; each XCD owns 2 adjacent 160-col B panels
  const int flat = blockIdx.x;
  const int xcd = flat & 7;
  const int local = flat >> 3;           // 0..63
  const int nb = xcd * 2 + (local & 1);  // 16 N-blocks
  const int mb = local >> 1;             // 32 M-blocks
  const int row0 = mb * 128, col0 = nb * 160;
  const int wr = w >> 1, wcn = w & 1;

  // stage source swizzle (elements): inverse of LDS read swizzle
  const int srow = lane >> 3;
  const int srcsw = ((((lane & 7) << 4) ^ ((lane >> 3) << 4)) >> 1);

  // fragment read addressing
  const int fr = lane & 15;
  const int csw0 = ((((lane >> 4) << 4)) ^ ((lane & 7) << 4)) >> 1;       // kk=0
  const int csw1 = ((64 + ((lane >> 4) << 4)) ^ ((lane & 7) << 4)) >> 1;  // kk=1

  f32x4 acc[4][5] = {};
  bf16x8 afA0[2][2], afA1[2][2], afB[2][2];
  bf16x8 bqA0[3][2], bqA1[3][2], bqB[2][2];

  // prologue: tile 0 fully (9 units) + tile 1's {u4,u5,u2,u3}; frag reads
  STAGE_U(0, 0, 0); STAGE_U(0, 1, 0); STAGE_U(0, 2, 0); STAGE_U(0, 3, 0);
  STAGE_U(0, 4, 0); STAGE_U(0, 5, 0); STAGE_U(0, 6, 0); STAGE_U(0, 7, 0);
  STAGE_U(0, 8, 0);
  STAGE_U(1, 4, 1); STAGE_U(1, 5, 1); STAGE_U(1, 2, 1); STAGE_U(1, 3, 1);
  asm volatile("s_waitcnt vmcnt(4)" ::: "memory");  // tile 0 landed
  __builtin_amdgcn_s_barrier();
  SB();
  LOAD_AF(afA0, 0, 0);
  LOAD_BQA(bqA0, 0);
  SB();

  for (int T2 = 0; T2 < NKT; T2 += 2) {
    TILE_BODY(0, afA0, bqA0, afA1, bqA1);
    TILE_BODY(1, afA1, bqA1, afA0, bqA0);
  }
  // drain ALL outstanding LDS traffic (dup staging + dead frag reads), then
  // repurpose LDS for the epilogue bounce buffer.
  asm volatile("s_waitcnt vmcnt(0) lgkmcnt(0)" ::: "memory");
  __builtin_amdgcn_s_barrier();

  // ---------------- coalesced epilogue ----------------
  // acc layout: value (m,n,j) -> row = wr*64 + m*16 + (lane>>4)*4 + j,
  //                              col = wcn*80 + n*16 + fr   (within block tile)
  if (MODE == 0) {
    // stage bf16 [128][160] = 40KB into LDS, then 2560 x 16B coalesced stores
    unsigned short* eb = &lds[0][0];
#pragma unroll
    for (int n = 0; n < 5; ++n) {
      const int col = wcn * 80 + n * 16 + fr;
      const float bv = bias0[col0 + col];
#pragma unroll
      for (int m = 0; m < 4; ++m) {
        const int rbase = wr * 64 + m * 16 + ((lane >> 4) << 2);
#pragma unroll
        for (int j = 0; j < 4; ++j) {
          float v = fmaxf(acc[m][n][j] + bv, 0.0f);
          eb[(rbase + j) * 160 + col] = f2bf(v);
        }
      }
    }
    __builtin_amdgcn_s_barrier();
    unsigned short* Co = (unsigned short*)C;
#pragma unroll
    for (int r = 0; r < 10; ++r) {
      const int u = tid + r * 256;
      const int off = u * 8;              // elements; 20 units per 160-el row
      const int row = off / 160;
      const int cole = off % 160;
      bf16x8 v = *reinterpret_cast<const bf16x8*>(eb + off);
      *reinterpret_cast<bf16x8*>(Co + (long)(row0 + row) * INNER + col0 + cole) = v;
    }
  } else {
    // f32 outputs, two 64-row halves (40KB each)
    float* outO = (float*)C;                          // [4096,512]
    float* outH = (float*)C + (long)BATCH * OUT_SZ;   // [4096,2048]
    float* eb4 = (float*)&lds[0][0];
#pragma unroll
    for (int h2 = 0; h2 < 2; ++h2) {
      if (wr == h2) {
#pragma unroll
        for (int n = 0; n < 5; ++n) {
          const int col = wcn * 80 + n * 16 + fr;
          const int gc = col0 + col;
          const float bv = (gc < OUT_SZ) ? bias0[gc] : bias1[gc - OUT_SZ];
#pragma unroll
          for (int m = 0; m < 4; ++m) {
            const int rbase = m * 16 + ((lane >> 4) << 2);  // 0..63 in half
#pragma unroll
            for (int j = 0; j < 4; ++j) {
              float v = acc[m][n][j] + bv;
              if (gc >= OUT_SZ) v = tanhf(v);
              eb4[(rbase + j) * 160 + col] = v;
            }
          }
        }
      }
      __builtin_amdgcn_s_barrier();
#pragma unroll
      for (int r = 0; r < 10; ++r) {
        const int u = tid + r * 256;
        const int off4 = u * 4;           // f32 elements; 40 units per row
        const int row = off4 / 160;
        const int cole = off4 % 160;
        const int gc = col0 + cole;
        float4 v = *reinterpret_cast<const float4*>(eb4 + off4);
        const int grow = row0 + h2 * 64 + row;
        if (gc < OUT_SZ)
          *reinterpret_cast<float4*>(outO + (long)grow * OUT_SZ + gc) = v;
        else
          *reinterpret_cast<float4*>(outH + (long)grow * HID_SZ + (gc - OUT_SZ)) = v;
      }
      __builtin_amdgcn_s_barrier();
    }
  }
}

// ---------------- launcher ----------------

extern "C" void kernel_launch(void* const* d_in, const int* in_sizes, int n_in,
                              void* d_out, int out_size, void* d_ws, size_t ws_size,
                              hipStream_t stream) {
  const float* x   = (const float*)d_in[0];
  const float* h   = (const float*)d_in[1];
  const float* Wl  = (const float*)d_in[2];  // [4,2560,2560]
  const float* bl  = (const float*)d_in[3];  // [4,2560]
  const float* Wih = (const float*)d_in[4];  // [2048,2560]
  const float* bih = (const float*)d_in[5];  // [2048]
  const float* Wio = (const float*)d_in[6];  // [512,2560]
  const float* bio = (const float*)d_in[7];  // [512]

  unsigned short* ws   = (unsigned short*)d_ws;
  unsigned short* Wlb  = ws;                                   // 4*2560*2560
  unsigned short* Whb  = Wlb + (long)NLAYER * INNER * INNER;   // fused heads [2560][2560]
  unsigned short* act0 = Whb + (long)INNER * INNER;
  unsigned short* act1 = act0 + (long)BATCH * INNER;

  // fp32 -> bf16 weight conversion (dst contiguous: Wl ++ Wio ++ Wih)
  cvt_all<<<2048, 256, 0, stream>>>(Wl, Wih, Wio, Wlb);
  build_combined<<<2048, 256, 0, stream>>>(x, h, act0);

  // 4 square layers, ping-pong
  unsigned short* a_in = act0;
  unsigned short* a_out = act1;
  for (int l = 0; l < NLAYER; ++l) {
    gemm8<0><<<512, 256, 0, stream>>>(a_in, Wlb + (long)l * INNER * INNER,
                                      bl + (long)l * INNER, nullptr, a_out);
    unsigned short* t = a_in; a_in = a_out; a_out = t;
  }

  // fused heads: output (cols 0-511) + tanh hidden (cols 512-2559)
  gemm8<1><<<512, 256, 0, stream>>>(a_in, Whb, bio, bih, d_out);
}